// Round 8
// baseline (477.416 us; speedup 1.0000x reference)
//
#include <hip/hip_runtime.h>
#include <cstdint>
#include <cstddef>

#define Bn   128
#define Rn   500
#define Nn   500
#define Kn   10
#define En   128
#define H1n  640
#define KEn  1280
#define Mn   (Bn * Rn)   // 64000 rows

typedef short s16x8 __attribute__((ext_vector_type(8)));
typedef float f32x4 __attribute__((ext_vector_type(4)));

// fp32 -> bf16 round-to-nearest-even (finite inputs)
__device__ __forceinline__ unsigned short f2bf(float x) {
    union { float f; unsigned int u; } v; v.f = x;
    unsigned int r = v.u + 0x7fffu + ((v.u >> 16) & 1u);
    return (unsigned short)(r >> 16);
}
__device__ __forceinline__ float bf2f(unsigned short u) {
    union { unsigned int u; float f; } v; v.u = ((unsigned int)u) << 16;
    return v.f;
}
// async 16B global->LDS (wave-uniform LDS base + lane*16)
__device__ __forceinline__ void gl2lds16(const void* g, void* l) {
    __builtin_amdgcn_global_load_lds(
        (const __attribute__((address_space(1))) unsigned int*)g,
        (__attribute__((address_space(3))) unsigned int*)l, 16, 0, 0);
}
// full drain (prologue cleanup only — never in main loops)
__device__ __forceinline__ void drain_all() {
    asm volatile("s_waitcnt vmcnt(0) lgkmcnt(0)" ::: "memory");
}
// counted vmcnt: retire oldest (outstanding-N) VMEM ops, keep N in flight
// ACROSS barriers (T4). vmcnt retires in issue order (m135).
#define WAITV(n) asm volatile("s_waitcnt vmcnt(" #n ")" ::: "memory")
// bare barrier: NO implicit vmcnt(0) drain (unlike __syncthreads)
__device__ __forceinline__ void pipe_barrier() {
    __builtin_amdgcn_s_barrier();
    asm volatile("" ::: "memory");
}

// ---------------- kernel 1: fp32 -> bf16 conversions (encoded, w1, w2) ----------------
__global__ void convw_kernel(const float* __restrict__ enc, const float* __restrict__ w1,
                             const float* __restrict__ w2,
                             unsigned short* __restrict__ encb, unsigned short* __restrict__ w1b,
                             unsigned short* __restrict__ w2b) {
    int i = blockIdx.x * 256 + threadIdx.x;   // float4 group index
    if (i < (Bn * Nn * En) / 4) {
        float4 v = ((const float4*)enc)[i];
        ushort4 o; o.x = f2bf(v.x); o.y = f2bf(v.y); o.z = f2bf(v.z); o.w = f2bf(v.w);
        ((ushort4*)encb)[i] = o;
    }
    if (i < (H1n * KEn) / 4) {
        float4 v = ((const float4*)w1)[i];
        ushort4 o; o.x = f2bf(v.x); o.y = f2bf(v.y); o.z = f2bf(v.z); o.w = f2bf(v.w);
        ((ushort4*)w1b)[i] = o;
    }
    if (i < (En * H1n) / 4) {
        float4 v = ((const float4*)w2)[i];
        ushort4 o; o.x = f2bf(v.x); o.y = f2bf(v.y); o.z = f2bf(v.z); o.w = f2bf(v.w);
        ((ushort4*)w2b)[i] = o;
    }
}

// ---------------- kernel 2: fused top-K + pad-avg mean (4-row/wave pipeline) ----------
// R7 lesson: VALU cut was ~null — select is memory-LATENCY-serialized (occ 85%,
// VALU 32%, HBM 20%). R8: each wave processes 4 rows with a 2-deep software
// pipeline: row i+1's four independent uint4 loads are issued BEFORE row i's
// compact/sort/mean, so ~900cy of load latency hides under ~1300cy of work.
// current[] for all 4 rows prefetched up-front. Grid: Mn/16 = 4000 blocks.
__global__ __launch_bounds__(256) void select_kernel(const int* __restrict__ current,
                            const float* __restrict__ distance,
                            const float* __restrict__ masked,
                            const unsigned short* __restrict__ encb,
                            int* __restrict__ idx_out,
                            unsigned short* __restrict__ meanbb) {
    __shared__ unsigned long long buf[4][512];   // per-wave slice, reused across 4 rows
    const int wv    = threadIdx.x >> 6;
    const int lane  = threadIdx.x & 63;
    const int rbase = blockIdx.x * 16 + wv * 4;  // 4 consecutive rows per wave
    unsigned long long* wbuf = buf[wv];
    const unsigned long long INFKEY = 0x7F800000FFFFFFFFull;

    // prefetch all 4 current values (breaks current->dist addr dependence early)
    int curv[4];
#pragma unroll
    for (int i = 0; i < 4; ++i) curv[i] = current[rbase + i];

    // 2-slot staging registers (static-indexed: row loop fully unrolled)
    uint4 mu[2][2], du[2][2];

    auto issue_row = [&](int i, int slot) {
        const int r   = rbase + i;
        const int b   = r / Rn;
        const uint4* drow4 = (const uint4*)(distance + ((size_t)b * Nn + curv[i]) * Nn);
        const uint4* mrow4 = (const uint4*)(masked + (size_t)r * Nn);
#pragma unroll
        for (int h = 0; h < 2; ++h) {
            const int c = lane + 64 * h;
            mu[slot][h] = make_uint4(0xFF800000u, 0xFF800000u, 0xFF800000u, 0xFF800000u);
            du[slot][h] = make_uint4(0u, 0u, 0u, 0u);
            if (c < 125) { mu[slot][h] = mrow4[c]; du[slot][h] = drow4[c]; }
        }
    };

    issue_row(0, 0);

#pragma unroll
    for (int i = 0; i < 4; ++i) {
        const int slot = i & 1;
        if (i + 1 < 4) issue_row(i + 1, slot ^ 1);   // overlap next row's loads
        const int r = rbase + i;
        const int b = r / Rn;

        // ---- build 8 keys + finite bitmask (consumes slot's regs; compiler
        //      waits only on THIS slot's loads, next slot's stay in flight) ----
        unsigned long long keyr[8];
        unsigned int fm = 0;
#pragma unroll
        for (int h = 0; h < 2; ++h) {
            const unsigned int mm[4] = {mu[slot][h].x, mu[slot][h].y, mu[slot][h].z, mu[slot][h].w};
            const unsigned int dd[4] = {du[slot][h].x, du[slot][h].y, du[slot][h].z, du[slot][h].w};
#pragma unroll
            for (int j = 0; j < 4; ++j) {
                const int e  = h * 4 + j;
                const int nn = 4 * (lane + 64 * h) + j;
                keyr[e] = ((unsigned long long)dd[j] << 32) | (unsigned int)nn;
                fm |= (mm[j] != 0xFF800000u ? 1u : 0u) << e;
            }
        }
        const int lc = __popc(fm);

        // ---- one exclusive wave prefix over per-lane counts ----
        int x = lc;
#pragma unroll
        for (int d = 1; d < 64; d <<= 1) {
            const int y = __shfl_up(x, d);
            if (lane >= d) x += y;
        }
        const int n = __shfl(x, 63);
        int off = x - lc;

        // ---- <=8 conditional LDS writes at running offset (wave-private) ----
#pragma unroll
        for (int e = 0; e < 8; ++e) {
            if (fm & (1u << e)) wbuf[off++] = keyr[e];
        }

        int ids[Kn];       // wave-uniform winners, ascending distance
        if (n <= 64) {
            // ---- bitonic sort; skip the k=64 merge when n<=32 (P~1e-4) ----
            unsigned long long key = (lane < n) ? wbuf[lane] : INFKEY;
#pragma unroll
            for (int k = 2; k <= 32; k <<= 1) {
#pragma unroll
                for (int j = k >> 1; j >= 1; j >>= 1) {
                    const unsigned long long ok = __shfl_xor(key, j);
                    const bool takemin = (((lane & k) == 0) == ((lane & j) == 0));
                    const unsigned long long mn = (ok < key) ? ok : key;
                    const unsigned long long mx = (ok < key) ? key : ok;
                    key = takemin ? mn : mx;
                }
            }
            if (n > 32) {
#pragma unroll
                for (int j = 32; j >= 1; j >>= 1) {
                    const unsigned long long ok = __shfl_xor(key, j);
                    const bool takemin = (((lane & 64) == 0) == ((lane & j) == 0));
                    const unsigned long long mn = (ok < key) ? ok : key;
                    const unsigned long long mx = (ok < key) ? key : ok;
                    key = takemin ? mn : mx;
                }
            }
            const int wid = ((unsigned int)(key >> 32) >= 0x7F800000u) ? Nn
                                                                       : (int)(key & 0xffffffffu);
            if (lane < Kn) idx_out[r * Kn + lane] = wid;
#pragma unroll
            for (int k = 0; k < Kn; ++k) ids[k] = __shfl(wid, k);
        } else {
            // ---- fallback: knockout min-reduction over compacted list ----
            unsigned long long key8[8];
#pragma unroll
            for (int q = 0; q < 8; ++q) {
                const int ii = lane + 64 * q;
                key8[q] = (ii < n) ? wbuf[ii] : INFKEY;
            }
            int myid = Nn;
#pragma unroll
            for (int it = 0; it < Kn; ++it) {
                unsigned long long bk = key8[0];
#pragma unroll
                for (int q = 1; q < 8; ++q) bk = (key8[q] < bk) ? key8[q] : bk;
#pragma unroll
                for (int off2 = 1; off2 < 64; off2 <<= 1) {
                    const unsigned long long ok = __shfl_xor(bk, off2);
                    bk = (ok < bk) ? ok : bk;
                }
                const int wid = ((unsigned int)(bk >> 32) >= 0x7F800000u) ? Nn
                                                                          : (int)(bk & 0xffffffffu);
                ids[it] = wid;
                if (lane == it) myid = wid;
#pragma unroll
                for (int q = 0; q < 8; ++q)
                    if (key8[q] == bk) key8[q] = INFKEY;
            }
            if (lane < Kn) idx_out[r * Kn + lane] = myid;
        }

        // ---- mean phase: lane handles embedding dims {2*lane, 2*lane+1} ----
        const unsigned int* encu = (const unsigned int*)(encb + (size_t)b * Nn * En);
        float s0 = 0.f, s1 = 0.f; int cnt = 0;
#pragma unroll
        for (int k = 0; k < Kn; ++k) {
            const int id = ids[k];
            if (id < Nn) {
                unsigned int u = encu[id * (En / 2) + lane];
                s0 += bf2f((unsigned short)(u & 0xffffu));
                s1 += bf2f((unsigned short)(u >> 16));
                cnt++;
            }
        }
        float m0 = 0.f, m1 = 0.f;
        if (cnt > 0) { m0 = s0 / (float)cnt; m1 = s1 / (float)cnt; }
        unsigned int packed = (unsigned int)f2bf(m0) | ((unsigned int)f2bf(m1) << 16);
        ((unsigned int*)meanbb)[(size_t)r * (En / 2) + lane] = packed;
    }
}

// ---------------- kernel 3: GEMM1, 8-wave 256x128, BK=32, triple-buffer, 2 blocks/CU ----
// R5-exact (banked best: 113 us, MfmaUtil 41, 0 bank conflicts). The merged
// single-barrier variant regressed gemm1 (+31 us, R6) — do not re-apply here.
__global__ __launch_bounds__(512, 4) void gemm1_kernel(
        const unsigned short* __restrict__ encb, const unsigned short* __restrict__ meanbb,
        const int* __restrict__ idxb, const unsigned short* __restrict__ w1b,
        const float* __restrict__ b1, unsigned short* __restrict__ hbuf) {
    extern __shared__ unsigned short lds[];
    unsigned short* const As   = lds;                              // 3 * 256*32
    unsigned short* const Bs   = lds + 3 * 256 * 32;               // 3 * 128*32
    unsigned short* const idxs = lds + 3 * 256 * 32 + 3 * 128 * 32; // 2560 u16

    // bijective XCD chunk map (nwg=1250, 8 XCDs: q=156, r=2)
    const int p  = blockIdx.x;
    const int x  = p & 7;
    const int rk = p >> 3;
    const int w  = (x < 2 ? x * 157 : 314 + (x - 2) * 156) + rk;
    const int row0 = (w / 5) * 256;
    const int h0   = (w % 5) * 128;

    const int t    = threadIdx.x;
    const int lane = t & 63;
    const int wave = t >> 6;    // 0..7
    const int ln15 = lane & 15;
    const int q4   = lane >> 4;
    const int wm4  = wave & 3;  // M position (4)
    const int wn   = wave >> 2; // N position (2)

    // stage neighbor ids (256 rows x 10) as u16 into LDS
    for (int i = t; i < 256 * Kn; i += 512)
        idxs[i] = (unsigned short)idxb[row0 * Kn + i];

    // staging geometry: row = 32 shorts = 64 B = 4 x 16B slots.
    // lane -> row rl = lane>>2, slot sc = lane&3; slot sc holds chunk sc^((rl>>1)&3).
    const int rl   = lane >> 2;
    const int sc   = lane & 3;
    const int coff = (sc ^ ((rl >> 1) & 3)) * 8;   // source chunk offset (shorts)

    int lrowA[2];
    const unsigned short* encB[2];
    const unsigned short* meanR[2];
#pragma unroll
    for (int s = 0; s < 2; ++s) {
        lrowA[s] = wave * 32 + s * 16 + rl;
        const int gr = row0 + lrowA[s];
        encB[s]  = encb + (size_t)(gr / Rn) * Nn * En;
        meanR[s] = meanbb + (size_t)gr * En + coff;
    }
    const int lrowB = wave * 16 + rl;
    const unsigned short* w1R = w1b + (size_t)(h0 + lrowB) * KEn + coff;

    f32x4 acc[4][4];
#pragma unroll
    for (int i = 0; i < 4; ++i)
#pragma unroll
        for (int j = 0; j < 4; ++j)
            acc[i][j] = (f32x4){0.f, 0.f, 0.f, 0.f};

    // per tile: issueA = 2 loads (A rows), issueB = 1 load (B rows): 3/thread
    auto issueA = [&](int kt, int cb) {
        const int j  = kt >> 2;             // neighbor slot
        const int e0 = (kt & 3) * 32;       // quarter of embedding row
#pragma unroll
        for (int s = 0; s < 2; ++s) {
            const int id = idxs[lrowA[s] * Kn + j];
            const unsigned short* src = (id < Nn)
                ? (encB[s] + (size_t)id * En + e0 + coff)
                : (meanR[s] + e0);
            gl2lds16(src, As + (size_t)cb * (256 * 32) + (wave * 32 + s * 16) * 32);
        }
    };
    auto issueB = [&](int kt, int cb) {
        gl2lds16(w1R + kt * 32, Bs + (size_t)cb * (128 * 32) + (wave * 16) * 32);
    };

    drain_all();
    __syncthreads();          // idxs visible; vmcnt clean slate
    issueA(0, 0); issueB(0, 0);
    issueA(1, 1); issueB(1, 1);
    WAITV(3);                 // tile0's 3 landed; tile1's 3 stay in flight
    pipe_barrier();

    const int rA  = wm4 * 64 + ln15;
    const int rB  = wn  * 64 + ln15;
    const int slA = (q4 ^ ((rA >> 1) & 3)) * 8;   // constant across +16-row steps
    const int slB = (q4 ^ ((rB >> 1) & 3)) * 8;

#define MFMA16(a, bvec, c) c = __builtin_amdgcn_mfma_f32_16x16x32_bf16(a, bvec, c, 0, 0, 0)

#pragma unroll
    for (int kt = 0; kt < 40; ++kt) {
        const int cb = kt % 3;
        const unsigned short* Ab = As + cb * (256 * 32);
        const unsigned short* Bb = Bs + cb * (128 * 32);
        s16x8 af0, af1, af2, af3, bq0, bq1;

        // ---- phase 0: jj=0..1  (+ stage A of kt+2)
        af0 = *(const s16x8*)(Ab + (rA +  0) * 32 + slA);
        af1 = *(const s16x8*)(Ab + (rA + 16) * 32 + slA);
        af2 = *(const s16x8*)(Ab + (rA + 32) * 32 + slA);
        af3 = *(const s16x8*)(Ab + (rA + 48) * 32 + slA);
        bq0 = *(const s16x8*)(Bb + (rB +  0) * 32 + slB);
        bq1 = *(const s16x8*)(Bb + (rB + 16) * 32 + slB);
        if (kt + 2 < 40) issueA(kt + 2, (kt + 2) % 3);
        pipe_barrier();
        __builtin_amdgcn_s_setprio(1);
        MFMA16(af0, bq0, acc[0][0]); MFMA16(af1, bq0, acc[1][0]);
        MFMA16(af2, bq0, acc[2][0]); MFMA16(af3, bq0, acc[3][0]);
        MFMA16(af0, bq1, acc[0][1]); MFMA16(af1, bq1, acc[1][1]);
        MFMA16(af2, bq1, acc[2][1]); MFMA16(af3, bq1, acc[3][1]);
        __builtin_amdgcn_s_setprio(0);
        pipe_barrier();

        // ---- phase 1: jj=2..3  (+ stage B of kt+2, counted tile-end wait)
        bq0 = *(const s16x8*)(Bb + (rB + 32) * 32 + slB);
        bq1 = *(const s16x8*)(Bb + (rB + 48) * 32 + slB);
        if (kt + 2 < 40) issueB(kt + 2, (kt + 2) % 3);
        pipe_barrier();
        __builtin_amdgcn_s_setprio(1);
        MFMA16(af0, bq0, acc[0][2]); MFMA16(af1, bq0, acc[1][2]);
        MFMA16(af2, bq0, acc[2][2]); MFMA16(af3, bq0, acc[3][2]);
        MFMA16(af0, bq1, acc[0][3]); MFMA16(af1, bq1, acc[1][3]);
        MFMA16(af2, bq1, acc[2][3]); MFMA16(af3, bq1, acc[3][3]);
        __builtin_amdgcn_s_setprio(0);
        // retire kt+1's 3 loads; keep kt+2's 3 in flight (never 0 mid-loop)
        if (kt + 2 < 40)      { WAITV(3); }
        else if (kt + 1 < 40) { WAITV(0); }   // tail: no kt+2 issued
        pipe_barrier();
    }
#undef MFMA16

    // ---- epilogue: bias + relu + bf16 store ----
#pragma unroll
    for (int i = 0; i < 4; ++i) {
#pragma unroll
        for (int jj = 0; jj < 4; ++jj) {
            const int h = h0 + wn * 64 + jj * 16 + ln15;
            const float bias = b1[h];
#pragma unroll
            for (int rg = 0; rg < 4; ++rg) {
                const int m = wm4 * 64 + i * 16 + q4 * 4 + rg;
                float vv = acc[i][jj][rg] + bias;
                vv = fmaxf(vv, 0.f);
                hbuf[(size_t)(row0 + m) * H1n + h] = f2bf(vv);
            }
        }
    }
}

// ---------------- kernel 4: GEMM2, merged single-barrier (R6 variant, −9 us evid.) -----
// gemm2 has ~2 blocks/CU on a 500-block grid; fewer alignment points helped it
// in the R6 A/B even though the same merge hurt gemm1.
__global__ __launch_bounds__(256, 4) void gemm2_kernel(
        const unsigned short* __restrict__ hbuf, const unsigned short* __restrict__ w2b,
        const float* __restrict__ b2, float* __restrict__ out) {
    __shared__ alignas(16) unsigned short As[3][128 * 32];
    __shared__ alignas(16) unsigned short Bs[3][128 * 32];

    const int row0 = blockIdx.x * 128;
    const int t    = threadIdx.x;
    const int lane = t & 63;
    const int wave = t >> 6;    // 0..3
    const int ln15 = lane & 15;
    const int q4   = lane >> 4;
    const int wm   = wave & 1;
    const int wn   = wave >> 1;

    const int rl   = lane >> 2;
    const int sc   = lane & 3;
    const int coff = (sc ^ ((rl >> 1) & 3)) * 8;

    const unsigned short* hrow[2];
    const unsigned short* w2row[2];
#pragma unroll
    for (int s = 0; s < 2; ++s) {
        const int lr = wave * 32 + s * 16 + rl;
        hrow[s]  = hbuf + (size_t)(row0 + lr) * H1n + coff;
        w2row[s] = w2b + (size_t)lr * H1n + coff;
    }

    f32x4 acc[4][4];
#pragma unroll
    for (int i = 0; i < 4; ++i)
#pragma unroll
        for (int j = 0; j < 4; ++j)
            acc[i][j] = (f32x4){0.f, 0.f, 0.f, 0.f};

    auto issueA = [&](int kt, int cb) {
#pragma unroll
        for (int s = 0; s < 2; ++s)
            gl2lds16(hrow[s] + kt * 32, &As[cb][(wave * 32 + s * 16) * 32]);
    };
    auto issueB = [&](int kt, int cb) {
#pragma unroll
        for (int s = 0; s < 2; ++s)
            gl2lds16(w2row[s] + kt * 32, &Bs[cb][(wave * 32 + s * 16) * 32]);
    };

    issueA(0, 0); issueB(0, 0);
    issueA(1, 1); issueB(1, 1);
    WAITV(4);                 // tile0's 4 landed; tile1's 4 in flight
    pipe_barrier();

    const int rA  = wm * 64 + ln15;
    const int rB  = wn * 64 + ln15;
    const int slA = (q4 ^ ((rA >> 1) & 3)) * 8;
    const int slB = (q4 ^ ((rB >> 1) & 3)) * 8;

#define MFMA16(a, bvec, c) c = __builtin_amdgcn_mfma_f32_16x16x32_bf16(a, bvec, c, 0, 0, 0)

#pragma unroll
    for (int kt = 0; kt < 20; ++kt) {
        const int cb = kt % 3;
        const unsigned short* Ab = As[cb];
        const unsigned short* Bb = Bs[cb];
        s16x8 af0, af1, af2, af3, bq0, bq1, bq2, bq3;

        af0 = *(const s16x8*)(Ab + (rA +  0) * 32 + slA);
        af1 = *(const s16x8*)(Ab + (rA + 16) * 32 + slA);
        af2 = *(const s16x8*)(Ab + (rA + 32) * 32 + slA);
        af3 = *(const s16x8*)(Ab + (rA + 48) * 32 + slA);
        bq0 = *(const s16x8*)(Bb + (rB +  0) * 32 + slB);
        bq1 = *(const s16x8*)(Bb + (rB + 16) * 32 + slB);
        bq2 = *(const s16x8*)(Bb + (rB + 32) * 32 + slB);
        bq3 = *(const s16x8*)(Bb + (rB + 48) * 32 + slB);
        if (kt + 2 < 20) { issueA(kt + 2, (kt + 2) % 3); issueB(kt + 2, (kt + 2) % 3); }
        __builtin_amdgcn_s_setprio(1);
        MFMA16(af0, bq0, acc[0][0]); MFMA16(af1, bq0, acc[1][0]);
        MFMA16(af2, bq0, acc[2][0]); MFMA16(af3, bq0, acc[3][0]);
        MFMA16(af0, bq1, acc[0][1]); MFMA16(af1, bq1, acc[1][1]);
        MFMA16(af2, bq1, acc[2][1]); MFMA16(af3, bq1, acc[3][1]);
        MFMA16(af0, bq2, acc[0][2]); MFMA16(af1, bq2, acc[1][2]);
        MFMA16(af2, bq2, acc[2][2]); MFMA16(af3, bq2, acc[3][2]);
        MFMA16(af0, bq3, acc[0][3]); MFMA16(af1, bq3, acc[1][3]);
        MFMA16(af2, bq3, acc[2][3]); MFMA16(af3, bq3, acc[3][3]);
        __builtin_amdgcn_s_setprio(0);
        if (kt + 2 < 20)      { WAITV(4); }
        else if (kt + 1 < 20) { WAITV(0); }
        pipe_barrier();
    }
#undef MFMA16

#pragma unroll
    for (int i = 0; i < 4; ++i) {
#pragma unroll
        for (int jj = 0; jj < 4; ++jj) {
            const int e = wn * 64 + jj * 16 + ln15;
            const float bias = b2[e];
#pragma unroll
            for (int rg = 0; rg < 4; ++rg) {
                const int m = wm * 64 + i * 16 + q4 * 4 + rg;
                out[(size_t)(row0 + m) * En + e] = acc[i][jj][rg] + bias;
            }
        }
    }
}

// ---------------- launch ----------------
extern "C" void kernel_launch(void* const* d_in, const int* in_sizes, int n_in,
                              void* d_out, int out_size, void* d_ws, size_t ws_size,
                              hipStream_t stream) {
    const int*   current  = (const int*)d_in[0];
    const float* distance = (const float*)d_in[1];
    const float* masked   = (const float*)d_in[2];
    const float* encoded  = (const float*)d_in[3];
    const float* w1       = (const float*)d_in[4];
    const float* b1       = (const float*)d_in[5];
    const float* w2       = (const float*)d_in[6];
    const float* b2       = (const float*)d_in[7];
    float* out = (float*)d_out;

    char* ws = (char*)d_ws;
    const size_t OFF_IDX  = 0;                          // 64000*10*4   = 2,560,000
    const size_t OFF_ENCB = 2560000;                    // 8,192,000*2  = 16,384,000
    const size_t OFF_MEAN = OFF_ENCB + 16384000;        // 64000*128*2  = 16,384,000
    const size_t OFF_W1B  = OFF_MEAN + 16384000;        // 819200*2     = 1,638,400
    const size_t OFF_W2B  = OFF_W1B + 1638400;          // 81920*2      = 163,840
    const size_t OFF_H    = OFF_W2B + 163840;           // 64000*640*2  = 81,920,000
    int*            idxb   = (int*)(ws + OFF_IDX);
    unsigned short* encb   = (unsigned short*)(ws + OFF_ENCB);
    unsigned short* meanbb = (unsigned short*)(ws + OFF_MEAN);
    unsigned short* w1b    = (unsigned short*)(ws + OFF_W1B);
    unsigned short* w2b    = (unsigned short*)(ws + OFF_W2B);
    unsigned short* hbuf   = (unsigned short*)(ws + OFF_H);

    // gemm1 dynamic LDS: 3*(16KB A + 8KB B) + 5KB idx = 78848 B (2 blocks/CU)
    static bool s_attr = false;
    if (!s_attr) {
        hipFuncSetAttribute(reinterpret_cast<const void*>(gemm1_kernel),
                            hipFuncAttributeMaxDynamicSharedMemorySize, 78848);
        s_attr = true;
    }

    convw_kernel<<<(Bn * Nn * En / 4 + 255) / 256, 256, 0, stream>>>(encoded, w1, w2, encb, w1b, w2b);
    select_kernel<<<Mn / 16, 256, 0, stream>>>(current, distance, masked, encb, idxb, meanbb);
    gemm1_kernel<<<1250, 512, 78848, stream>>>(encb, meanbb, idxb, w1b, b1, hbuf);
    gemm2_kernel<<<Mn / 128, 256, 0, stream>>>(hbuf, w2b, b2, out);
}

// Round 9
// 423.106 us; speedup vs baseline: 1.1284x; 1.1284x over previous
//
#include <hip/hip_runtime.h>
#include <cstdint>
#include <cstddef>

#define Bn   128
#define Rn   500
#define Nn   500
#define Kn   10
#define En   128
#define H1n  640
#define KEn  1280
#define Mn   (Bn * Rn)   // 64000 rows

typedef short s16x8 __attribute__((ext_vector_type(8)));
typedef float f32x4 __attribute__((ext_vector_type(4)));

// fp32 -> bf16 round-to-nearest-even (finite inputs)
__device__ __forceinline__ unsigned short f2bf(float x) {
    union { float f; unsigned int u; } v; v.f = x;
    unsigned int r = v.u + 0x7fffu + ((v.u >> 16) & 1u);
    return (unsigned short)(r >> 16);
}
__device__ __forceinline__ float bf2f(unsigned short u) {
    union { unsigned int u; float f; } v; v.u = ((unsigned int)u) << 16;
    return v.f;
}
// async 16B global->LDS (wave-uniform LDS base + lane*16)
__device__ __forceinline__ void gl2lds16(const void* g, void* l) {
    __builtin_amdgcn_global_load_lds(
        (const __attribute__((address_space(1))) unsigned int*)g,
        (__attribute__((address_space(3))) unsigned int*)l, 16, 0, 0);
}
// full drain (prologue cleanup only — never in main loops)
__device__ __forceinline__ void drain_all() {
    asm volatile("s_waitcnt vmcnt(0) lgkmcnt(0)" ::: "memory");
}
// counted vmcnt: retire oldest (outstanding-N) VMEM ops, keep N in flight
// ACROSS barriers (T4). vmcnt retires in issue order (m135).
#define WAITV(n) asm volatile("s_waitcnt vmcnt(" #n ")" ::: "memory")
// bare barrier: NO implicit vmcnt(0) drain (unlike __syncthreads)
__device__ __forceinline__ void pipe_barrier() {
    __builtin_amdgcn_s_barrier();
    asm volatile("" ::: "memory");
}

// ---------------- kernel 1: fp32 -> bf16 conversions (encoded, w1, w2) ----------------
__global__ void convw_kernel(const float* __restrict__ enc, const float* __restrict__ w1,
                             const float* __restrict__ w2,
                             unsigned short* __restrict__ encb, unsigned short* __restrict__ w1b,
                             unsigned short* __restrict__ w2b) {
    int i = blockIdx.x * 256 + threadIdx.x;   // float4 group index
    if (i < (Bn * Nn * En) / 4) {
        float4 v = ((const float4*)enc)[i];
        ushort4 o; o.x = f2bf(v.x); o.y = f2bf(v.y); o.z = f2bf(v.z); o.w = f2bf(v.w);
        ((ushort4*)encb)[i] = o;
    }
    if (i < (H1n * KEn) / 4) {
        float4 v = ((const float4*)w1)[i];
        ushort4 o; o.x = f2bf(v.x); o.y = f2bf(v.y); o.z = f2bf(v.z); o.w = f2bf(v.w);
        ((ushort4*)w1b)[i] = o;
    }
    if (i < (En * H1n) / 4) {
        float4 v = ((const float4*)w2)[i];
        ushort4 o; o.x = f2bf(v.x); o.y = f2bf(v.y); o.z = f2bf(v.z); o.w = f2bf(v.w);
        ((ushort4*)w2b)[i] = o;
    }
}

// ---------------- kernel 2: fused top-K + pad-avg mean (R7 + mean-skip) ----------------
// R8 lesson: cutting TLP for an ILP pipeline regressed (occupancy 85->42) — this
// kernel's regime is occupancy-driven throughput. R9 = R7-exact (1 row/wave,
// grid Mn/4) + wave-uniform mean-skip: the mean is only consumed by gemm1 for
// pad slots, which exist iff n < Kn (~8% of rows). 92% of rows skip the
// 10-row gather + store entirely.
__global__ __launch_bounds__(256) void select_kernel(const int* __restrict__ current,
                            const float* __restrict__ distance,
                            const float* __restrict__ masked,
                            const unsigned short* __restrict__ encb,
                            int* __restrict__ idx_out,
                            unsigned short* __restrict__ meanbb) {
    __shared__ unsigned long long buf[4][512];   // per-wave slices
    const int wv   = threadIdx.x >> 6;
    const int row  = blockIdx.x * 4 + wv;
    const int lane = threadIdx.x & 63;
    const int b    = row / Rn;
    const int cur  = current[row];
    const uint4* drow4 = (const uint4*)(distance + ((size_t)b * Nn + cur) * Nn);
    const uint4* mrow4 = (const uint4*)(masked + (size_t)row * Nn);
    unsigned long long* wbuf = buf[wv];
    const unsigned long long INFKEY = 0x7F800000FFFFFFFFull;

    // ---- parallel vectorized loads: 2 x uint4 mask + 2 x uint4 dist per lane ----
    uint4 mu[2], du[2];
#pragma unroll
    for (int h = 0; h < 2; ++h) {
        const int c = lane + 64 * h;
        mu[h] = make_uint4(0xFF800000u, 0xFF800000u, 0xFF800000u, 0xFF800000u);
        du[h] = make_uint4(0u, 0u, 0u, 0u);
        if (c < 125) { mu[h] = mrow4[c]; du[h] = drow4[c]; }
    }

    // ---- build 8 keys (static regs) + finite bitmask ----
    unsigned long long keyr[8];
    unsigned int fm = 0;
#pragma unroll
    for (int h = 0; h < 2; ++h) {
        const unsigned int mm[4] = {mu[h].x, mu[h].y, mu[h].z, mu[h].w};
        const unsigned int dd[4] = {du[h].x, du[h].y, du[h].z, du[h].w};
#pragma unroll
        for (int j = 0; j < 4; ++j) {
            const int e  = h * 4 + j;
            const int nn = 4 * (lane + 64 * h) + j;
            keyr[e] = ((unsigned long long)dd[j] << 32) | (unsigned int)nn;
            fm |= (mm[j] != 0xFF800000u ? 1u : 0u) << e;
        }
    }
    const int lc = __popc(fm);

    // ---- one exclusive wave prefix over per-lane counts ----
    int x = lc;
#pragma unroll
    for (int d = 1; d < 64; d <<= 1) {
        const int y = __shfl_up(x, d);
        if (lane >= d) x += y;
    }
    const int n = __shfl(x, 63);     // total finite keys (wave-uniform)
    int off = x - lc;                // this lane's exclusive prefix

    // ---- <=8 conditional LDS writes at running offset (wave-private slice) ----
#pragma unroll
    for (int e = 0; e < 8; ++e) {
        if (fm & (1u << e)) wbuf[off++] = keyr[e];
    }
    // NO __syncthreads(): wave reads only its own wbuf slice (lgkm-ordered).

    if (n <= 64) {
        // ---- bitonic sort across lanes; skip the k=64 merge when n<=32 ----
        unsigned long long key = (lane < n) ? wbuf[lane] : INFKEY;
#pragma unroll
        for (int k = 2; k <= 32; k <<= 1) {
#pragma unroll
            for (int j = k >> 1; j >= 1; j >>= 1) {
                const unsigned long long ok = __shfl_xor(key, j);
                const bool takemin = (((lane & k) == 0) == ((lane & j) == 0));
                const unsigned long long mn = (ok < key) ? ok : key;
                const unsigned long long mx = (ok < key) ? key : ok;
                key = takemin ? mn : mx;
            }
        }
        if (n > 32) {                      // wave-uniform branch, ~1e-4 of rows
#pragma unroll
            for (int j = 32; j >= 1; j >>= 1) {
                const unsigned long long ok = __shfl_xor(key, j);
                const bool takemin = (((lane & 64) == 0) == ((lane & j) == 0));
                const unsigned long long mn = (ok < key) ? ok : key;
                const unsigned long long mx = (ok < key) ? key : ok;
                key = takemin ? mn : mx;
            }
        }
        const int wid = ((unsigned int)(key >> 32) >= 0x7F800000u) ? Nn
                                                                   : (int)(key & 0xffffffffu);
        if (lane < Kn) idx_out[row * Kn + lane] = wid;

        // ---- mean phase ONLY when a pad slot exists (n < Kn, ~8% of rows) ----
        if (n < Kn) {
            int ids[Kn];
#pragma unroll
            for (int k = 0; k < Kn; ++k) ids[k] = __shfl(wid, k);
            const unsigned int* encu = (const unsigned int*)(encb + (size_t)b * Nn * En);
            float s0 = 0.f, s1 = 0.f; int cnt = 0;
#pragma unroll
            for (int k = 0; k < Kn; ++k) {
                const int id = ids[k];
                if (id < Nn) {
                    unsigned int u = encu[id * (En / 2) + lane];
                    s0 += bf2f((unsigned short)(u & 0xffffu));
                    s1 += bf2f((unsigned short)(u >> 16));
                    cnt++;
                }
            }
            float m0 = 0.f, m1 = 0.f;
            if (cnt > 0) { m0 = s0 / (float)cnt; m1 = s1 / (float)cnt; }
            unsigned int packed = (unsigned int)f2bf(m0) | ((unsigned int)f2bf(m1) << 16);
            ((unsigned int*)meanbb)[(size_t)row * (En / 2) + lane] = packed;
        }
    } else {
        // ---- fallback (n>64): knockout; n>=Kn so no pad slots, no mean needed ----
        unsigned long long key8[8];
#pragma unroll
        for (int i = 0; i < 8; ++i) {
            const int ii = lane + 64 * i;
            key8[i] = (ii < n) ? wbuf[ii] : INFKEY;
        }
        int myid = Nn;
#pragma unroll
        for (int it = 0; it < Kn; ++it) {
            unsigned long long bk = key8[0];
#pragma unroll
            for (int i = 1; i < 8; ++i) bk = (key8[i] < bk) ? key8[i] : bk;
#pragma unroll
            for (int off2 = 1; off2 < 64; off2 <<= 1) {
                const unsigned long long ok = __shfl_xor(bk, off2);
                bk = (ok < bk) ? ok : bk;
            }
            const int wid = ((unsigned int)(bk >> 32) >= 0x7F800000u) ? Nn
                                                                      : (int)(bk & 0xffffffffu);
            if (lane == it) myid = wid;
#pragma unroll
            for (int i = 0; i < 8; ++i)
                if (key8[i] == bk) key8[i] = INFKEY;
        }
        if (lane < Kn) idx_out[row * Kn + lane] = myid;
    }
}

// ---------------- kernel 3: GEMM1, 8-wave 256x128, BK=32, triple-buffer, 2 blocks/CU ----
// R9: per-K-tile idx/address work hoisted to prologue — 20 resolved 32-bit
// source offsets (meanbb is contiguous after encb in ws, so `encb + off`
// covers both enc-gather and mean-pad paths). idxs LDS buffer and its staging
// barrier removed. Pipeline (counted WAITV(3), 4 barriers/tile) is R5-exact.
__global__ __launch_bounds__(512, 4) void gemm1_kernel(
        const unsigned short* __restrict__ encb, const unsigned short* __restrict__ meanbb,
        const int* __restrict__ idxb, const unsigned short* __restrict__ w1b,
        const float* __restrict__ b1, unsigned short* __restrict__ hbuf) {
    extern __shared__ unsigned short lds[];
    unsigned short* const As = lds;                    // 3 * 256*32
    unsigned short* const Bs = lds + 3 * 256 * 32;     // 3 * 128*32

    // bijective XCD chunk map (nwg=1250, 8 XCDs: q=156, r=2)
    const int p  = blockIdx.x;
    const int x  = p & 7;
    const int rk = p >> 3;
    const int w  = (x < 2 ? x * 157 : 314 + (x - 2) * 156) + rk;
    const int row0 = (w / 5) * 256;
    const int h0   = (w % 5) * 128;

    const int t    = threadIdx.x;
    const int lane = t & 63;
    const int wave = t >> 6;    // 0..7
    const int ln15 = lane & 15;
    const int q4   = lane >> 4;
    const int wm4  = wave & 3;  // M position (4)
    const int wn   = wave >> 2; // N position (2)

    // staging geometry: row = 32 shorts = 64 B = 4 x 16B slots.
    // lane -> row rl = lane>>2, slot sc = lane&3; slot sc holds chunk sc^((rl>>1)&3).
    const int rl   = lane >> 2;
    const int sc   = lane & 3;
    const int coff = (sc ^ ((rl >> 1) & 3)) * 8;   // source chunk offset (shorts)

    // resolved A-source offsets (shorts, relative to encb) for the 2 staged
    // rows x 10 neighbor slots. meanbb == encb + MEANOFF in ws (launch layout).
    const unsigned int MEANOFF = 8192000u;   // (OFF_MEAN - OFF_ENCB)/2 shorts
    unsigned int offA[2][Kn];
    int lrowA[2];
#pragma unroll
    for (int s = 0; s < 2; ++s) {
        lrowA[s] = wave * 32 + s * 16 + rl;
        const int gr = row0 + lrowA[s];
        const unsigned int encbase  = (unsigned int)((gr / Rn) * (Nn * En)) + (unsigned int)coff;
        const unsigned int meanbase = MEANOFF + (unsigned int)gr * En + (unsigned int)coff;
#pragma unroll
        for (int j = 0; j < Kn; ++j) {
            const int id = idxb[gr * Kn + j];
            offA[s][j] = (id < Nn) ? (encbase + (unsigned int)id * En) : meanbase;
        }
    }
    const int lrowB = wave * 16 + rl;
    const unsigned short* w1R = w1b + (size_t)(h0 + lrowB) * KEn + coff;

    f32x4 acc[4][4];
#pragma unroll
    for (int i = 0; i < 4; ++i)
#pragma unroll
        for (int j = 0; j < 4; ++j)
            acc[i][j] = (f32x4){0.f, 0.f, 0.f, 0.f};

    // per tile: issueA = 2 loads (A rows), issueB = 1 load (B rows): 3/thread.
    // j = kt>>2 is compile-time (fully unrolled loop) -> offA stays in regs.
    auto issueA = [&](int kt, int cb) {
        const int j  = kt >> 2;
        const int e0 = (kt & 3) * 32;
#pragma unroll
        for (int s = 0; s < 2; ++s)
            gl2lds16(encb + offA[s][j] + e0,
                     As + (size_t)cb * (256 * 32) + (wave * 32 + s * 16) * 32);
    };
    auto issueB = [&](int kt, int cb) {
        gl2lds16(w1R + kt * 32, Bs + (size_t)cb * (128 * 32) + (wave * 16) * 32);
    };

    WAITV(0);                 // idxb loads retired; vmcnt clean slate
    issueA(0, 0); issueB(0, 0);
    issueA(1, 1); issueB(1, 1);
    WAITV(3);                 // tile0's 3 landed; tile1's 3 stay in flight
    pipe_barrier();

    const int rA  = wm4 * 64 + ln15;
    const int rB  = wn  * 64 + ln15;
    const int slA = (q4 ^ ((rA >> 1) & 3)) * 8;   // constant across +16-row steps
    const int slB = (q4 ^ ((rB >> 1) & 3)) * 8;

#define MFMA16(a, bvec, c) c = __builtin_amdgcn_mfma_f32_16x16x32_bf16(a, bvec, c, 0, 0, 0)

#pragma unroll
    for (int kt = 0; kt < 40; ++kt) {
        const int cb = kt % 3;
        const unsigned short* Ab = As + cb * (256 * 32);
        const unsigned short* Bb = Bs + cb * (128 * 32);
        s16x8 af0, af1, af2, af3, bq0, bq1;

        // ---- phase 0: jj=0..1  (+ stage A of kt+2)
        af0 = *(const s16x8*)(Ab + (rA +  0) * 32 + slA);
        af1 = *(const s16x8*)(Ab + (rA + 16) * 32 + slA);
        af2 = *(const s16x8*)(Ab + (rA + 32) * 32 + slA);
        af3 = *(const s16x8*)(Ab + (rA + 48) * 32 + slA);
        bq0 = *(const s16x8*)(Bb + (rB +  0) * 32 + slB);
        bq1 = *(const s16x8*)(Bb + (rB + 16) * 32 + slB);
        if (kt + 2 < 40) issueA(kt + 2, (kt + 2) % 3);
        pipe_barrier();
        __builtin_amdgcn_s_setprio(1);
        MFMA16(af0, bq0, acc[0][0]); MFMA16(af1, bq0, acc[1][0]);
        MFMA16(af2, bq0, acc[2][0]); MFMA16(af3, bq0, acc[3][0]);
        MFMA16(af0, bq1, acc[0][1]); MFMA16(af1, bq1, acc[1][1]);
        MFMA16(af2, bq1, acc[2][1]); MFMA16(af3, bq1, acc[3][1]);
        __builtin_amdgcn_s_setprio(0);
        pipe_barrier();

        // ---- phase 1: jj=2..3  (+ stage B of kt+2, counted tile-end wait)
        bq0 = *(const s16x8*)(Bb + (rB + 32) * 32 + slB);
        bq1 = *(const s16x8*)(Bb + (rB + 48) * 32 + slB);
        if (kt + 2 < 40) issueB(kt + 2, (kt + 2) % 3);
        pipe_barrier();
        __builtin_amdgcn_s_setprio(1);
        MFMA16(af0, bq0, acc[0][2]); MFMA16(af1, bq0, acc[1][2]);
        MFMA16(af2, bq0, acc[2][2]); MFMA16(af3, bq0, acc[3][2]);
        MFMA16(af0, bq1, acc[0][3]); MFMA16(af1, bq1, acc[1][3]);
        MFMA16(af2, bq1, acc[2][3]); MFMA16(af3, bq1, acc[3][3]);
        __builtin_amdgcn_s_setprio(0);
        // retire kt+1's 3 loads; keep kt+2's 3 in flight (never 0 mid-loop)
        if (kt + 2 < 40)      { WAITV(3); }
        else if (kt + 1 < 40) { WAITV(0); }   // tail: no kt+2 issued
        pipe_barrier();
    }
#undef MFMA16

    // ---- epilogue: bias + relu + bf16 store ----
#pragma unroll
    for (int i = 0; i < 4; ++i) {
#pragma unroll
        for (int jj = 0; jj < 4; ++jj) {
            const int h = h0 + wn * 64 + jj * 16 + ln15;
            const float bias = b1[h];
#pragma unroll
            for (int rg = 0; rg < 4; ++rg) {
                const int m = wm4 * 64 + i * 16 + q4 * 4 + rg;
                float vv = acc[i][jj][rg] + bias;
                vv = fmaxf(vv, 0.f);
                hbuf[(size_t)(row0 + m) * H1n + h] = f2bf(vv);
            }
        }
    }
}

// ---------------- kernel 4: GEMM2, merged single-barrier (R7-exact, −9 us evid.) -------
__global__ __launch_bounds__(256, 4) void gemm2_kernel(
        const unsigned short* __restrict__ hbuf, const unsigned short* __restrict__ w2b,
        const float* __restrict__ b2, float* __restrict__ out) {
    __shared__ alignas(16) unsigned short As[3][128 * 32];
    __shared__ alignas(16) unsigned short Bs[3][128 * 32];

    const int row0 = blockIdx.x * 128;
    const int t    = threadIdx.x;
    const int lane = t & 63;
    const int wave = t >> 6;    // 0..3
    const int ln15 = lane & 15;
    const int q4   = lane >> 4;
    const int wm   = wave & 1;
    const int wn   = wave >> 1;

    const int rl   = lane >> 2;
    const int sc   = lane & 3;
    const int coff = (sc ^ ((rl >> 1) & 3)) * 8;

    const unsigned short* hrow[2];
    const unsigned short* w2row[2];
#pragma unroll
    for (int s = 0; s < 2; ++s) {
        const int lr = wave * 32 + s * 16 + rl;
        hrow[s]  = hbuf + (size_t)(row0 + lr) * H1n + coff;
        w2row[s] = w2b + (size_t)lr * H1n + coff;
    }

    f32x4 acc[4][4];
#pragma unroll
    for (int i = 0; i < 4; ++i)
#pragma unroll
        for (int j = 0; j < 4; ++j)
            acc[i][j] = (f32x4){0.f, 0.f, 0.f, 0.f};

    auto issueA = [&](int kt, int cb) {
#pragma unroll
        for (int s = 0; s < 2; ++s)
            gl2lds16(hrow[s] + kt * 32, &As[cb][(wave * 32 + s * 16) * 32]);
    };
    auto issueB = [&](int kt, int cb) {
#pragma unroll
        for (int s = 0; s < 2; ++s)
            gl2lds16(w2row[s] + kt * 32, &Bs[cb][(wave * 32 + s * 16) * 32]);
    };

    issueA(0, 0); issueB(0, 0);
    issueA(1, 1); issueB(1, 1);
    WAITV(4);                 // tile0's 4 landed; tile1's 4 in flight
    pipe_barrier();

    const int rA  = wm * 64 + ln15;
    const int rB  = wn * 64 + ln15;
    const int slA = (q4 ^ ((rA >> 1) & 3)) * 8;
    const int slB = (q4 ^ ((rB >> 1) & 3)) * 8;

#define MFMA16(a, bvec, c) c = __builtin_amdgcn_mfma_f32_16x16x32_bf16(a, bvec, c, 0, 0, 0)

#pragma unroll
    for (int kt = 0; kt < 20; ++kt) {
        const int cb = kt % 3;
        const unsigned short* Ab = As[cb];
        const unsigned short* Bb = Bs[cb];
        s16x8 af0, af1, af2, af3, bq0, bq1, bq2, bq3;

        af0 = *(const s16x8*)(Ab + (rA +  0) * 32 + slA);
        af1 = *(const s16x8*)(Ab + (rA + 16) * 32 + slA);
        af2 = *(const s16x8*)(Ab + (rA + 32) * 32 + slA);
        af3 = *(const s16x8*)(Ab + (rA + 48) * 32 + slA);
        bq0 = *(const s16x8*)(Bb + (rB +  0) * 32 + slB);
        bq1 = *(const s16x8*)(Bb + (rB + 16) * 32 + slB);
        bq2 = *(const s16x8*)(Bb + (rB + 32) * 32 + slB);
        bq3 = *(const s16x8*)(Bb + (rB + 48) * 32 + slB);
        if (kt + 2 < 20) { issueA(kt + 2, (kt + 2) % 3); issueB(kt + 2, (kt + 2) % 3); }
        __builtin_amdgcn_s_setprio(1);
        MFMA16(af0, bq0, acc[0][0]); MFMA16(af1, bq0, acc[1][0]);
        MFMA16(af2, bq0, acc[2][0]); MFMA16(af3, bq0, acc[3][0]);
        MFMA16(af0, bq1, acc[0][1]); MFMA16(af1, bq1, acc[1][1]);
        MFMA16(af2, bq1, acc[2][1]); MFMA16(af3, bq1, acc[3][1]);
        MFMA16(af0, bq2, acc[0][2]); MFMA16(af1, bq2, acc[1][2]);
        MFMA16(af2, bq2, acc[2][2]); MFMA16(af3, bq2, acc[3][2]);
        MFMA16(af0, bq3, acc[0][3]); MFMA16(af1, bq3, acc[1][3]);
        MFMA16(af2, bq3, acc[2][3]); MFMA16(af3, bq3, acc[3][3]);
        __builtin_amdgcn_s_setprio(0);
        if (kt + 2 < 20)      { WAITV(4); }
        else if (kt + 1 < 20) { WAITV(0); }
        pipe_barrier();
    }
#undef MFMA16

#pragma unroll
    for (int i = 0; i < 4; ++i) {
#pragma unroll
        for (int jj = 0; jj < 4; ++jj) {
            const int e = wn * 64 + jj * 16 + ln15;
            const float bias = b2[e];
#pragma unroll
            for (int rg = 0; rg < 4; ++rg) {
                const int m = wm * 64 + i * 16 + q4 * 4 + rg;
                out[(size_t)(row0 + m) * En + e] = acc[i][jj][rg] + bias;
            }
        }
    }
}

// ---------------- launch ----------------
extern "C" void kernel_launch(void* const* d_in, const int* in_sizes, int n_in,
                              void* d_out, int out_size, void* d_ws, size_t ws_size,
                              hipStream_t stream) {
    const int*   current  = (const int*)d_in[0];
    const float* distance = (const float*)d_in[1];
    const float* masked   = (const float*)d_in[2];
    const float* encoded  = (const float*)d_in[3];
    const float* w1       = (const float*)d_in[4];
    const float* b1       = (const float*)d_in[5];
    const float* w2       = (const float*)d_in[6];
    const float* b2       = (const float*)d_in[7];
    float* out = (float*)d_out;

    char* ws = (char*)d_ws;
    const size_t OFF_IDX  = 0;                          // 64000*10*4   = 2,560,000
    const size_t OFF_ENCB = 2560000;                    // 8,192,000*2  = 16,384,000
    const size_t OFF_MEAN = OFF_ENCB + 16384000;        // 64000*128*2  = 16,384,000
    const size_t OFF_W1B  = OFF_MEAN + 16384000;        // 819200*2     = 1,638,400
    const size_t OFF_W2B  = OFF_W1B + 1638400;          // 81920*2      = 163,840
    const size_t OFF_H    = OFF_W2B + 163840;           // 64000*640*2  = 81,920,000
    int*            idxb   = (int*)(ws + OFF_IDX);
    unsigned short* encb   = (unsigned short*)(ws + OFF_ENCB);
    unsigned short* meanbb = (unsigned short*)(ws + OFF_MEAN);   // == encb + 8,192,000 shorts
    unsigned short* w1b    = (unsigned short*)(ws + OFF_W1B);
    unsigned short* w2b    = (unsigned short*)(ws + OFF_W2B);
    unsigned short* hbuf   = (unsigned short*)(ws + OFF_H);

    // gemm1 dynamic LDS: 3*(16KB A + 8KB B) = 73728 B (2 blocks/CU)
    static bool s_attr = false;
    if (!s_attr) {
        hipFuncSetAttribute(reinterpret_cast<const void*>(gemm1_kernel),
                            hipFuncAttributeMaxDynamicSharedMemorySize, 73728);
        s_attr = true;
    }

    convw_kernel<<<(Bn * Nn * En / 4 + 255) / 256, 256, 0, stream>>>(encoded, w1, w2, encb, w1b, w2b);
    select_kernel<<<Mn / 4, 256, 0, stream>>>(current, distance, masked, encb, idxb, meanbb);
    gemm1_kernel<<<1250, 512, 73728, stream>>>(encb, meanbb, idxb, w1b, b1, hbuf);
    gemm2_kernel<<<Mn / 128, 256, 0, stream>>>(hbuf, w2b, b2, out);
}